// Round 5
// baseline (139.852 us; speedup 1.0000x reference)
//
#include <hip/hip_runtime.h>

// VQ-VAE VectorQuantizer forward for MI355X (gfx950) — MFMA-filtered argmin.
// z_e: (64, 256, 32, 32) fp32; codebook: (512, 256) fp32.
// Outputs concatenated in d_out (float32):
//   [0, 16777216)        z_q_st  (== z_e + (z_q - z_e), fp32 elementwise)
//   [16777216]           commitment_loss
//   [16777217]           codebook_loss (same value)
//   [16777218, +65536)   indices (as float)
//
// Index semantics: bitwise emulation of numpy-fp32
//   d = sum(z**2,axis=1,keepdims=True) + sum(e**2,axis=1) - 2*matmul(z, e.T)
//   idx = argmin(d, axis=1)   (first occurrence on exact fp32 ties)
// Strategy: bf16(hi)-only MFMA computes approximate scores (|err| << EPS/2);
// per-row candidates within EPS of the approx min are re-scored with the
// bitwise-exact sequential fp32 FMA chain (ascending d) and reduced with
// (d asc, tie -> lower k) — exactly numpy first-occurrence argmin. If a row
// overflows the candidate buffer, it falls back to an exact scan of all 512.

typedef __attribute__((ext_vector_type(8))) short short8v;
typedef __attribute__((ext_vector_type(4))) float float4v;
typedef unsigned short ushort_t;

namespace {
constexpr int K = 512;
constexpr int D = 256;
constexpr int HW = 1024;          // 32*32
constexpr int NROWS = 65536;      // 64*HW
constexpr int CHW = D * HW;       // 262144

constexpr int ZQ_SIZE = 64 * CHW; // 16777216
constexpr int LOSS0_OFF = ZQ_SIZE;
constexpr int LOSS1_OFF = ZQ_SIZE + 1;
constexpr int IDX_OFF = ZQ_SIZE + 2;

// workspace layout (float offsets)
constexpr int WS_EH_FLOATS = (K * D) / 2;  // eH bf16[512][256] = 65536 floats
constexpr int WS_B = WS_EH_FLOATS;         // ||e_k||^2 (numpy pairwise), 512
constexpr int WS_PART = WS_B + K;          // per-block loss partials, 2048
constexpr int NBLK = NROWS / 32;           // 2048 blocks of 32 rows

constexpr float EPS_CAND = 3.0e-3f;        // candidate window (>> 2*max err)
constexpr int MAXC = 16;                   // candidate slots per row
}  // namespace

__device__ __forceinline__ ushort_t bf16_rne(float f) {
    unsigned u = __float_as_uint(f);
    u += 0x7fffu + ((u >> 16) & 1u);   // round-to-nearest-even (no NaN in data)
    return (ushort_t)(u >> 16);
}

// ---------------------------------------------------------------------------
// Kernel 1: eH[k][d] = bf16(cb[k][d]); B[k] = ||e_k||^2 in numpy pairwise
// order: pw(x,256)=pw(x,128)+pw(x+128,128); pw(x,128): 8 accums x 16 strided
// adds, then ((r0+r1)+(r2+r3))+((r4+r5)+(r6+r7)).
__global__ void vq_prep(const float* __restrict__ cb, float* __restrict__ ws) {
    const int k = blockIdx.x;
    const int t = threadIdx.x;  // 0..255 == d
    ushort_t* eh = (ushort_t*)ws;
    eh[(size_t)k * D + t] = bf16_rne(cb[k * D + t]);
    __shared__ float r16[16];
    if (t < 16) {
#pragma clang fp contract(off)
        const float* x = cb + k * D + (t >> 3) * 128;
        const int j = t & 7;
        float v = x[j];
        float r = v * v;
        for (int i = 1; i < 16; ++i) {
            float w = x[8 * i + j];
            r += w * w;
        }
        r16[t] = r;
    }
    __syncthreads();
    if (t == 0) {
#pragma clang fp contract(off)
        float lo = ((r16[0] + r16[1]) + (r16[2] + r16[3])) +
                   ((r16[4] + r16[5]) + (r16[6] + r16[7]));
        float hi = ((r16[8] + r16[9]) + (r16[10] + r16[11])) +
                   ((r16[12] + r16[13]) + (r16[14] + r16[15]));
        ws[WS_B + k] = lo + hi;
    }
}

// ---------------------------------------------------------------------------
// Kernel 2 (mega): per 32-row block, ~24 KB LDS (5 blocks/CU):
//   exact pairwise A (global reads); bf16-hi of z -> LDS (global reads);
//   MFMA approx scores (4 waves x 128 codes x 32 rows, hi term only);
//   per-row approx min + candidate collection (<= min+EPS);
//   exact fp32-chain re-score of candidates (global z reads, sparse);
//   gather/straight-through write + loss partial (global z reads).
__global__ __launch_bounds__(256, 5) void vq_mega(
    const float* __restrict__ z_e, const float* __restrict__ cb,
    const ushort_t* __restrict__ eh, const float* __restrict__ Bv,
    float* __restrict__ part, float* __restrict__ out) {
    __shared__ __align__(16) ushort_t zh[32][264];    // 16.5 KB bf16 hi, padded
    __shared__ float lds_B[K];                        // 2 KB ||e_k||^2
    __shared__ float scr[32][17];                     // 2.1 KB pairwise accums
    __shared__ int cand[32][MAXC];                    // 2 KB candidate codes
    __shared__ float lds_A[32];
    __shared__ float wmin[4][32];
    __shared__ float rmin[32];
    __shared__ int cnt[32];
    __shared__ float wpart[4];

    const int t = threadIdx.x;
    const int row0 = blockIdx.x * 32;
    const int b = row0 >> 10;
    const int hw0 = row0 & 1023;
    const float* zbase = z_e + (size_t)b * CHW + hw0;

    // ---- B staging
    lds_B[t] = Bv[t];
    lds_B[t + 256] = Bv[t + 256];

    // ---- A = ||z_row||^2 in exact numpy pairwise order (2 chains/thread).
    // thread: row = t&31, q = t>>5 -> (half, j0); reads coalesce 128B/row-set.
    {
#pragma clang fp contract(off)
        const int row = t & 31;
        const int q = t >> 5;
        const int half = q >> 2;
        const int j0 = (q & 3) * 2;
        const float* zp = zbase + row + (size_t)(half * 128) * HW;
        float v0 = zp[(size_t)j0 * HW];
        float v1 = zp[(size_t)(j0 + 1) * HW];
        float r0 = v0 * v0;
        float r1 = v1 * v1;
        for (int i = 1; i < 16; ++i) {
            float w0 = zp[(size_t)(8 * i + j0) * HW];
            float w1 = zp[(size_t)(8 * i + j0 + 1) * HW];
            r0 += w0 * w0;
            r1 += w1 * w1;
        }
        scr[row][half * 8 + j0] = r0;
        scr[row][half * 8 + j0 + 1] = r1;
    }

    // ---- bf16-hi conversion of z -> zh[row][d] (coalesced global reads)
    {
        const int row = t & 31;
        const int dc = t >> 5;  // 0..7, 32 channels each
        const float* zp = zbase + row;
#pragma unroll
        for (int i = 0; i < 8; ++i) {
            const int d4 = dc * 32 + i * 4;
            float f0 = zp[(size_t)(d4 + 0) * HW];
            float f1 = zp[(size_t)(d4 + 1) * HW];
            float f2 = zp[(size_t)(d4 + 2) * HW];
            float f3 = zp[(size_t)(d4 + 3) * HW];
            uint2 ph;
            ph.x = (unsigned)bf16_rne(f0) | ((unsigned)bf16_rne(f1) << 16);
            ph.y = (unsigned)bf16_rne(f2) | ((unsigned)bf16_rne(f3) << 16);
            *reinterpret_cast<uint2*>(&zh[row][d4]) = ph;
        }
    }
    __syncthreads();
    if (t < 32) {
#pragma clang fp contract(off)
        const float* r = scr[t];
        float lo = ((r[0] + r[1]) + (r[2] + r[3])) + ((r[4] + r[5]) + (r[6] + r[7]));
        float hi = ((r[8] + r[9]) + (r[10] + r[11])) + ((r[12] + r[13]) + (r[14] + r[15]));
        lds_A[t] = lo + hi;
    }
    __syncthreads();

    // ---- MFMA main loop: wave w owns codes [w*128, w*128+128), all 32 rows.
    // A = E (codes = M), B = Z-hi (rows = N). hi term only.
    // C frag (m89-verified): col = lane&15 = z-row; row = 4*(lane>>4)+reg = code.
    const int lane = t & 63;
    const int w = t >> 6;
    const int wc0 = w * 128;
    const int l15 = lane & 15;
    const int kg = lane >> 4;

    float4v acc[8][2];
#pragma unroll
    for (int c = 0; c < 8; ++c)
#pragma unroll
        for (int rt = 0; rt < 2; ++rt) acc[c][rt] = (float4v)0.f;

    const ushort_t* ehp = eh + (size_t)(wc0 + l15) * D + 8 * kg;

#pragma unroll 4
    for (int d0 = 0; d0 < D; d0 += 32) {
        const short8v bh0 = *reinterpret_cast<const short8v*>(&zh[l15][d0 + 8 * kg]);
        const short8v bh1 = *reinterpret_cast<const short8v*>(&zh[16 + l15][d0 + 8 * kg]);
#pragma unroll
        for (int c = 0; c < 8; ++c) {
            const short8v a = *reinterpret_cast<const short8v*>(ehp + c * 16 * D + d0);
            acc[c][0] = __builtin_amdgcn_mfma_f32_16x16x32_bf16(a, bh0, acc[c][0], 0, 0, 0);
            acc[c][1] = __builtin_amdgcn_mfma_f32_16x16x32_bf16(a, bh1, acc[c][1], 0, 0, 0);
        }
    }

    // ---- approx scores + per-row min
    float lmin0 = 3.0e38f, lmin1 = 3.0e38f;
#pragma unroll
    for (int c = 0; c < 8; ++c)
#pragma unroll
        for (int rt = 0; rt < 2; ++rt)
#pragma unroll
            for (int r = 0; r < 4; ++r) {
                const int code = wc0 + 16 * c + 4 * kg + r;
                const int row = rt * 16 + l15;
                float s = (lds_A[row] + lds_B[code]) - 2.0f * acc[c][rt][r];
                acc[c][rt][r] = s;
                if (rt == 0) lmin0 = fminf(lmin0, s);
                else lmin1 = fminf(lmin1, s);
            }
    lmin0 = fminf(lmin0, __shfl_xor(lmin0, 16));
    lmin0 = fminf(lmin0, __shfl_xor(lmin0, 32));
    lmin1 = fminf(lmin1, __shfl_xor(lmin1, 16));
    lmin1 = fminf(lmin1, __shfl_xor(lmin1, 32));
    if (lane < 16) {
        wmin[w][l15] = lmin0;
        wmin[w][16 + l15] = lmin1;
    }
    __syncthreads();
    if (t < 32) {
        rmin[t] = fminf(fminf(wmin[0][t], wmin[1][t]), fminf(wmin[2][t], wmin[3][t]));
        cnt[t] = 0;
    }
    __syncthreads();

    // ---- candidate collection (any possible exact winner is within EPS)
#pragma unroll
    for (int c = 0; c < 8; ++c)
#pragma unroll
        for (int rt = 0; rt < 2; ++rt) {
            const int row = rt * 16 + l15;
            const float thr = rmin[row] + EPS_CAND;
#pragma unroll
            for (int r = 0; r < 4; ++r) {
                if (acc[c][rt][r] <= thr) {
                    const int code = wc0 + 16 * c + 4 * kg + r;
                    int slot = atomicAdd(&cnt[row], 1);
                    if (slot < MAXC) cand[row][slot] = code;
                }
            }
        }
    __syncthreads();

    // ---- exact pass: bitwise numpy-fp32 chain for rows with >=2 candidates.
    // zh buffer is dead now; alias reduction arrays onto it.
    float* ed = reinterpret_cast<float*>(&zh[0][0]);  // [8][32]
    int* ek = reinterpret_cast<int*>(ed + 256);       // [8][32]
    int* kb = ek + 256;                               // [32]
    {
        const int row = t & 31;
        const int ct = t >> 5;  // 0..7 candidate-threads per row
        const float* zp = zbase + row;
        const int n = cnt[row];
        float bd = 3.0e38f;
        int bk = 0x7fffffff;
        if (n == 1) {
            if (ct == 0) {
                bd = -3.0e38f;
                bk = cand[row][0];
            }
        } else {
            const bool full = (n > MAXC);  // overflow: exact-scan all codes
            const int lim = full ? K : n;
            for (int s = ct; s < lim; s += 8) {
                const int k = full ? s : cand[row][s];
                const float* ep = cb + (size_t)k * D;
                float a = 0.f;
#pragma unroll 8
                for (int c = 0; c < D; ++c) a = fmaf(zp[(size_t)c * HW], ep[c], a);
                float dv;
                {
#pragma clang fp contract(off)
                    float t1 = lds_A[row] + lds_B[k];
                    dv = t1 - 2.0f * a;
                }
                if (dv < bd || (dv == bd && k < bk)) {
                    bd = dv;
                    bk = k;
                }
            }
        }
        ed[t] = bd;
        ek[t] = bk;
    }
    __syncthreads();
    if (t < 32) {
        float bd = ed[t];
        int bk = ek[t];
#pragma unroll
        for (int q = 1; q < 8; ++q) {
            float od = ed[q * 32 + t];
            int ok = ek[q * 32 + t];
            if (od < bd || (od == bd && ok < bk)) {
                bd = od;
                bk = ok;
            }
        }
        kb[t] = bk;
        out[IDX_OFF + row0 + t] = (float)bk;
    }
    __syncthreads();

    // ---- gather / straight-through write / loss partial (z from global/L2)
    {
        const int j = t & 31;
        const int g = t >> 5;  // 0..7 -> c = g*32 + i
        const int kme = kb[j];
        const float* ep = cb + (size_t)kme * D;
        const float* zp = zbase + j;
        float* ob = out + (size_t)b * CHW + hw0 + j;
        float accum = 0.f;
#pragma unroll 4
        for (int i = 0; i < 32; ++i) {
            const int c = g * 32 + i;
            float z = zp[(size_t)c * HW];
            float e = ep[c];
            ob[(size_t)c * HW] = z + (e - z);
            float df = z - e;
            accum = fmaf(df, df, accum);
        }
#pragma unroll
        for (int m = 1; m < 64; m <<= 1) accum += __shfl_xor(accum, m);
        if ((t & 63) == 0) wpart[t >> 6] = accum;
    }
    __syncthreads();
    if (t == 0) part[blockIdx.x] = (wpart[0] + wpart[1]) + (wpart[2] + wpart[3]);
}

// ---------------------------------------------------------------------------
// Kernel 3: final loss reduction (2048 partials, fp64, deterministic).
__global__ void vq_finish(const float* __restrict__ part, float* __restrict__ out) {
    const int t = threadIdx.x;  // 256 threads
    double s = 0.0;
#pragma unroll
    for (int i = 0; i < 8; ++i) s += (double)part[t + 256 * i];
#pragma unroll
    for (int m = 1; m < 64; m <<= 1) s += __shfl_xor(s, m);
    __shared__ double wsum[4];
    if ((t & 63) == 0) wsum[t >> 6] = s;
    __syncthreads();
    if (t == 0) {
        double mean = (wsum[0] + wsum[1] + wsum[2] + wsum[3]) / (double)ZQ_SIZE;
        out[LOSS0_OFF] = (float)mean;
        out[LOSS1_OFF] = (float)mean;
    }
}

// ---------------------------------------------------------------------------
extern "C" void kernel_launch(void* const* d_in, const int* in_sizes, int n_in,
                              void* d_out, int out_size, void* d_ws, size_t ws_size,
                              hipStream_t stream) {
    const float* z_e = (const float*)d_in[0];
    const float* cb = (const float*)d_in[1];
    float* out = (float*)d_out;
    float* ws = (float*)d_ws;

    const ushort_t* eh = (const ushort_t*)ws;
    float* Bv = ws + WS_B;
    float* part = ws + WS_PART;

    vq_prep<<<K, D, 0, stream>>>(cb, ws);
    vq_mega<<<NBLK, 256, 0, stream>>>(z_e, cb, eh, Bv, part, out);
    vq_finish<<<1, 256, 0, stream>>>(part, out);
}